// Round 3
// baseline (2706.265 us; speedup 1.0000x reference)
//
#include <hip/hip_runtime.h>

#define B_ 128
#define T_ 512
#define D_ 256
#define H_ 512
#define GG_ 32   // gate groups: 16 hidden units each
#define BG_ 8    // batch groups: 16 rows each

typedef __bf16 bf16x8 __attribute__((ext_vector_type(8)));
typedef float  f32x4  __attribute__((ext_vector_type(4)));
typedef unsigned int u32;
typedef unsigned long long u64;

// h exchange: double-buffered, each element packed as (bf16 hi) | (bf16 lo << 16).
// Accessed ONLY via agent-scope relaxed atomics (L2-bypass) => no fences needed.
__device__ __align__(16) u32 g_h[2][B_ * H_];

__device__ inline float sigmoidf_(float v) { return 1.f / (1.f + __expf(-v)); }
__device__ inline float tanhf_(float v)    { return 1.f - 2.f / (__expf(2.f * v) + 1.f); }

// Grid: 256 blocks = 32 gate-groups x 8 batch-groups. Block: 256 threads = 4 waves.
// Wave w owns K-slice [w*64,w*64+64) of D and [w*128,w*128+128) of H.
// Each block computes gates for 16 batch rows x 64 gate rows (4 types x 16 units).
// Weights stay in registers (bf16 hi/lo B-fragments) for all 512 steps.
// Sync: per-(bg,gg) flag slots, 128B apart. Producer: ONE relaxed agent store of
// t+1. Consumer: lanes 0..31 of wave 0 poll 32 DISTINCT lines in parallel.
#define FSTRIDE 32   // u32s per flag slot (128 B)

__global__ __launch_bounds__(256, 1)
void lstm_persistent(const float* __restrict__ x,
                     const float* __restrict__ Wih,
                     const float* __restrict__ Whh,
                     const float* __restrict__ bih,
                     const float* __restrict__ bhh,
                     float* __restrict__ out,
                     u32* __restrict__ flags)
{
    const int tid  = threadIdx.x;
    const int wv   = tid >> 6;
    const int lane = tid & 63;
    const int gg   = blockIdx.x & (GG_ - 1);
    const int bg   = blockIdx.x / GG_;

    const int lm = lane & 15;   // M/N index in 16x16 MFMA tile
    const int lq = lane >> 4;   // k-quad (k offset = lq*8)

    // ---- Weight B-fragments in registers (bf16 hi/lo), loaded once ----
    bf16x8 wih_hi[2][4], wih_lo[2][4];   // [kt][gt], k = wv*64 + kt*32 + lq*8
    bf16x8 whh_hi[4][4], whh_lo[4][4];   // [kt][gt], k = wv*128 + kt*32 + lq*8

    for (int gt = 0; gt < 4; ++gt) {
        const int grow = gt * 512 + gg * 16 + lm;   // gate row (type=gt, unit=gg*16+lm)
#pragma unroll
        for (int kt = 0; kt < 2; ++kt) {
            const float* p = Wih + (size_t)grow * D_ + wv * 64 + kt * 32 + lq * 8;
            bf16x8 hi, lo;
#pragma unroll
            for (int e = 0; e < 8; ++e) {
                float v = p[e];
                __bf16 h1 = (__bf16)v;
                hi[e] = h1; lo[e] = (__bf16)(v - (float)h1);
            }
            wih_hi[kt][gt] = hi; wih_lo[kt][gt] = lo;
        }
#pragma unroll
        for (int kt = 0; kt < 4; ++kt) {
            const float* p = Whh + (size_t)grow * H_ + wv * 128 + kt * 32 + lq * 8;
            bf16x8 hi, lo;
#pragma unroll
            for (int e = 0; e < 8; ++e) {
                float v = p[e];
                __bf16 h1 = (__bf16)v;
                hi[e] = h1; lo[e] = (__bf16)(v - (float)h1);
            }
            whh_hi[kt][gt] = hi; whh_lo[kt][gt] = lo;
        }
    }

    // ---- Pointwise mapping: unit pj = tid&15, batch row pb = tid>>4 ----
    const int pj = tid & 15;
    const int pb = tid >> 4;
    float bias[4];
#pragma unroll
    for (int tp = 0; tp < 4; ++tp) {
        const int r = tp * 512 + gg * 16 + pj;
        bias[tp] = bih[r] + bhh[r];
    }
    float c = 0.f;

    __shared__ __align__(16) float gp[4][64][17];   // [wave][gate row][batch(+pad)]

    const int   xrow   = bg * 16 + lm;
    const float* xbase = x + (size_t)xrow * T_ * D_ + wv * 64;
    const u32 hoff_r = (u32)(bg * 16 + lm) * H_ + wv * 128;   // consumer fragment base
    const u32 hoff_w = (u32)(bg * 16 + pb) * H_ + gg * 16 + pj;
    u32* const myflag   = &flags[(u32)(bg * GG_ + gg) * FSTRIDE];
    const u32* pollflag = &flags[(u32)(bg * GG_ + (lane & (GG_ - 1))) * FSTRIDE];

    for (int t = 0; t < T_; ++t) {
        f32x4 acc[4];
#pragma unroll
        for (int gt = 0; gt < 4; ++gt) acc[gt] = (f32x4){0.f, 0.f, 0.f, 0.f};

        // ---- x-part (independent of h; issued before the wait) ----
        const float* px = xbase + (size_t)t * D_;
#pragma unroll
        for (int kt = 0; kt < 2; ++kt) {
            const float* p = px + kt * 32 + lq * 8;
            f32x4 v0 = *(const f32x4*)p;
            f32x4 v1 = *(const f32x4*)(p + 4);
            bf16x8 ahi, alo;
#pragma unroll
            for (int e = 0; e < 4; ++e) {
                __bf16 h1 = (__bf16)v0[e];
                ahi[e] = h1; alo[e] = (__bf16)(v0[e] - (float)h1);
                __bf16 h2 = (__bf16)v1[e];
                ahi[e + 4] = h2; alo[e + 4] = (__bf16)(v1[e] - (float)h2);
            }
#pragma unroll
            for (int gt = 0; gt < 4; ++gt) {
                acc[gt] = __builtin_amdgcn_mfma_f32_16x16x32_bf16(ahi, wih_hi[kt][gt], acc[gt], 0, 0, 0);
                acc[gt] = __builtin_amdgcn_mfma_f32_16x16x32_bf16(ahi, wih_lo[kt][gt], acc[gt], 0, 0, 0);
                acc[gt] = __builtin_amdgcn_mfma_f32_16x16x32_bf16(alo, wih_hi[kt][gt], acc[gt], 0, 0, 0);
            }
        }

        // ---- h-part: wait for step t-1 producers (parallel flag poll) ----
        if (t > 0) {
            if (wv == 0) {
                while (__hip_atomic_load(pollflag, __ATOMIC_RELAXED,
                                         __HIP_MEMORY_SCOPE_AGENT) < (u32)t)
                    __builtin_amdgcn_s_sleep(1);
            }
            __syncthreads();

            const u32* hp = &g_h[(t - 1) & 1][hoff_r];
#pragma unroll
            for (int kt = 0; kt < 4; ++kt) {
                const u32* q = hp + kt * 32 + lq * 8;
                u64 q0 = __hip_atomic_load((const u64*)(q + 0), __ATOMIC_RELAXED, __HIP_MEMORY_SCOPE_AGENT);
                u64 q1 = __hip_atomic_load((const u64*)(q + 2), __ATOMIC_RELAXED, __HIP_MEMORY_SCOPE_AGENT);
                u64 q2 = __hip_atomic_load((const u64*)(q + 4), __ATOMIC_RELAXED, __HIP_MEMORY_SCOPE_AGENT);
                u64 q3 = __hip_atomic_load((const u64*)(q + 6), __ATOMIC_RELAXED, __HIP_MEMORY_SCOPE_AGENT);
                u32 wd[8] = {(u32)q0, (u32)(q0 >> 32), (u32)q1, (u32)(q1 >> 32),
                             (u32)q2, (u32)(q2 >> 32), (u32)q3, (u32)(q3 >> 32)};
                bf16x8 ahi, alo;
#pragma unroll
                for (int e = 0; e < 8; ++e) {
                    ahi[e] = __builtin_bit_cast(__bf16, (unsigned short)(wd[e] & 0xffffu));
                    alo[e] = __builtin_bit_cast(__bf16, (unsigned short)(wd[e] >> 16));
                }
#pragma unroll
                for (int gt = 0; gt < 4; ++gt) {
                    acc[gt] = __builtin_amdgcn_mfma_f32_16x16x32_bf16(ahi, whh_hi[kt][gt], acc[gt], 0, 0, 0);
                    acc[gt] = __builtin_amdgcn_mfma_f32_16x16x32_bf16(ahi, whh_lo[kt][gt], acc[gt], 0, 0, 0);
                    acc[gt] = __builtin_amdgcn_mfma_f32_16x16x32_bf16(alo, whh_hi[kt][gt], acc[gt], 0, 0, 0);
                }
            }
        }

        // ---- cross-wave K reduction via LDS ----
#pragma unroll
        for (int gt = 0; gt < 4; ++gt)
            *(f32x4*)&gp[wv][gt * 16 + lm][lq * 4] = acc[gt];   // C/D: col=lm(gate), row=lq*4+reg(batch)
        __syncthreads();

        float gate[4];
#pragma unroll
        for (int tp = 0; tp < 4; ++tp) {
            const int g = tp * 16 + pj;
            gate[tp] = gp[0][g][pb] + gp[1][g][pb] + gp[2][g][pb] + gp[3][g][pb] + bias[tp];
        }
        const float ig = sigmoidf_(gate[0]);
        const float fg = sigmoidf_(gate[1]);
        const float gv = tanhf_(gate[2]);
        const float og = sigmoidf_(gate[3]);
        c = fg * c + ig * gv;
        const float h = og * tanhf_(c);

        // ---- publish h (critical path), THEN signal, THEN the out store ----
        const __bf16 hh = (__bf16)h;
        const __bf16 hl = (__bf16)(h - (float)hh);
        const u32 packed = (u32)__builtin_bit_cast(unsigned short, hh) |
                           ((u32)__builtin_bit_cast(unsigned short, hl) << 16);
        __hip_atomic_store(&g_h[t & 1][hoff_w], packed, __ATOMIC_RELAXED, __HIP_MEMORY_SCOPE_AGENT);

        if (t < T_ - 1) {
            __builtin_amdgcn_s_waitcnt(0);   // drain h stores to the coherence point
            __syncthreads();                 // all waves drained
            if (tid == 0)
                __hip_atomic_store(myflag, (u32)(t + 1), __ATOMIC_RELAXED,
                                   __HIP_MEMORY_SCOPE_AGENT);
        }

        out[((size_t)t * B_ + bg * 16 + pb) * H_ + gg * 16 + pj] = h;
    }
}

extern "C" void kernel_launch(void* const* d_in, const int* in_sizes, int n_in,
                              void* d_out, int out_size, void* d_ws, size_t ws_size,
                              hipStream_t stream) {
    const float* x   = (const float*)d_in[0];
    const float* Wih = (const float*)d_in[1];
    const float* Whh = (const float*)d_in[2];
    const float* bih = (const float*)d_in[3];
    const float* bhh = (const float*)d_in[4];
    float* out = (float*)d_out;
    u32* flags = (u32*)d_ws;

    // flag slots: 8 bg x 32 gg x 128 B = 32 KB, must start at 0 (ws poisoned 0xAA)
    hipMemsetAsync(d_ws, 0, BG_ * GG_ * FSTRIDE * sizeof(u32), stream);
    hipLaunchKernelGGL(lstm_persistent, dim3(GG_ * BG_), dim3(256), 0, stream,
                       x, Wih, Whh, bih, bhh, out, flags);
}